// Round 7
// baseline (237.384 us; speedup 1.0000x reference)
//
#include <hip/hip_runtime.h>
#include <math.h>

#define BATCH 128
#define SEQ   2048
#define HID   1024
#define CDIM  256
#define SPLIT 16
#define ROWS_PER (SEQ / SPLIT)   // 128
#define KC1   16                 // mlp1 k-chunks (each 64)
#define KC2   4                  // mlp2 k-chunks (each 256)

typedef float vf4 __attribute__((ext_vector_type(4)));
typedef int   vi4 __attribute__((ext_vector_type(4)));

// ---------------------------------------------------------------------------
// Kernel 1: partial masked sums + per-chunk mask counts.
// grid (BATCH, SPLIT), block 256. Thread t owns float4 at h = t*4.
// R7 change: PLAIN loads (no nontemporal hint) — A/B test vs R6; nt-tagged
// reads may bypass L2 burst aggregation and cap stream BW.
// ---------------------------------------------------------------------------
__global__ __launch_bounds__(256) void pool_partial_kernel(
    const float* __restrict__ feat, const int* __restrict__ mask,
    float* __restrict__ partial, int* __restrict__ cntp,
    unsigned* __restrict__ tkt_loss)
{
    const int b     = blockIdx.x;
    const int chunk = blockIdx.y;
    const int t     = threadIdx.x;

    const vf4* fp = reinterpret_cast<const vf4*>(feat) +
                    ((size_t)b * SEQ + (size_t)chunk * ROWS_PER) * (HID / 4);
    const vi4* mp = reinterpret_cast<const vi4*>(
                        mask + (size_t)b * SEQ + (size_t)chunk * ROWS_PER);

    vf4 acc = {0.f, 0.f, 0.f, 0.f};
    int csum = 0;
    for (int s = 0; s < ROWS_PER; s += 8) {
        const vi4 m0 = mp[s / 4];
        const vi4 m1 = mp[s / 4 + 1];
        csum += m0.x + m0.y + m0.z + m0.w + m1.x + m1.y + m1.z + m1.w;
        float mm[8];
        mm[0] = (float)m0.x; mm[1] = (float)m0.y; mm[2] = (float)m0.z; mm[3] = (float)m0.w;
        mm[4] = (float)m1.x; mm[5] = (float)m1.y; mm[6] = (float)m1.z; mm[7] = (float)m1.w;
        #pragma unroll
        for (int u = 0; u < 8; ++u) {
            const vf4 v = fp[(size_t)(s + u) * (HID / 4) + t];   // plain load
            acc += v * mm[u];
        }
    }
    reinterpret_cast<vf4*>(partial)[((size_t)b * SPLIT + chunk) * (HID / 4) + t] = acc;
    if (t == 0) {
        cntp[b * SPLIT + chunk] = csum;
        if (b == 0 && chunk == 0) *tkt_loss = 0u;
    }
}

// ---------------------------------------------------------------------------
// Kernel 2: fused {pool finalize 8x64 slice} + mlp1 split-K GEMM. No fences —
// reads partial/cntp written by the previous dispatch (boundary coherence).
// grid (4 jc, 16 bg, 16 kc) = 1024 blocks, block 256.
// Staging uses ALL 256 threads: halves split the 16 partial chunks.
// ---------------------------------------------------------------------------
__global__ __launch_bounds__(256) void mlp1_fused_kernel(
    const float* __restrict__ partial, const int* __restrict__ cntp,
    const float* __restrict__ W1, float* __restrict__ part1)
{
    const int jc = blockIdx.x;
    const int bg = blockIdx.y;
    const int kc = blockIdx.z;
    const int t  = threadIdx.x;

    __shared__ float psA[8][64];  // 2 KiB
    __shared__ float psB[8][64];  // 2 KiB
    __shared__ float invs[8];

    const int half = t >> 7;      // 0 or 1
    const int idx  = t & 127;
    const int r    = idx >> 4;    // 0..7
    const int c4   = idx & 15;    // 0..15

    const vf4* pp = reinterpret_cast<const vf4*>(partial);
    const size_t base = ((size_t)(bg * 8 + r) * SPLIT + half * 8) * (HID / 4)
                        + (size_t)kc * 16 + c4;
    vf4 a = {0.f, 0.f, 0.f, 0.f};
    #pragma unroll
    for (int p = 0; p < 8; ++p)
        a += pp[base + (size_t)p * (HID / 4)];

    if (t < 8) {
        const int* cp = cntp + (size_t)(bg * 8 + t) * SPLIT;
        int c = 0;
        #pragma unroll
        for (int p = 0; p < SPLIT; ++p) c += cp[p];
        invs[t] = 1.0f / (float)c;
    }

    float* dst = half ? &psB[0][0] : &psA[0][0];
    *reinterpret_cast<vf4*>(dst + r * 64 + c4 * 4) = a;
    __syncthreads();

    if (half == 0) {
        vf4 s = (*reinterpret_cast<vf4*>(&psA[r][c4 * 4]) +
                 *reinterpret_cast<vf4*>(&psB[r][c4 * 4])) * invs[r];
        *reinterpret_cast<vf4*>(&psA[r][c4 * 4]) = s;
    }
    __syncthreads();

    const int j = jc * 256 + t;
    const float* w = W1 + (size_t)(kc * 64) * HID + j;

    float acc[8];
    #pragma unroll
    for (int rr = 0; rr < 8; ++rr) acc[rr] = 0.f;

    #pragma unroll
    for (int k = 0; k < 64; k += 8) {
        float wv[8];
        #pragma unroll
        for (int u = 0; u < 8; ++u) wv[u] = w[(size_t)(k + u) * HID];
        #pragma unroll
        for (int u = 0; u < 8; ++u) {
            #pragma unroll
            for (int rr = 0; rr < 8; ++rr)
                acc[rr] = fmaf(psA[rr][k + u], wv[u], acc[rr]);
        }
    }
    #pragma unroll
    for (int rr = 0; rr < 8; ++rr)
        part1[((size_t)kc * BATCH + bg * 8 + rr) * HID + j] = acc[rr];
}

// ---------------------------------------------------------------------------
// Kernel 3: fused {reduce part1 + bias + relu} staging, then mlp2 split-K.
// grid (BATCH, KC2) = 512 blocks, block 256. part2[kc][b][j].
// ---------------------------------------------------------------------------
__global__ __launch_bounds__(256) void mlp2_partial_kernel(
    const float* __restrict__ part1, const float* __restrict__ b1,
    const float* __restrict__ W2, float* __restrict__ part2)
{
    const int b  = blockIdx.x;
    const int kc = blockIdx.y;
    const int t  = threadIdx.x;

    __shared__ float hs[256];  // 1 KiB
    float s = b1[kc * 256 + t];
    #pragma unroll
    for (int p = 0; p < KC1; ++p)
        s += part1[((size_t)p * BATCH + b) * HID + kc * 256 + t];
    hs[t] = fmaxf(s, 0.f);
    __syncthreads();

    const float* w = W2 + (size_t)(kc * 256) * CDIM + t;
    float acc = 0.f;
    #pragma unroll
    for (int k = 0; k < 256; k += 8) {
        float wv[8];
        #pragma unroll
        for (int u = 0; u < 8; ++u) wv[u] = w[(size_t)(k + u) * CDIM];
        #pragma unroll
        for (int u = 0; u < 8; ++u) acc = fmaf(hs[k + u], wv[u], acc);
    }
    part2[((size_t)kc * BATCH + b) * CDIM + t] = acc;
}

// ---------------------------------------------------------------------------
// Kernel 4: reduce part2 + bias + L2-normalize -> proj (d_out).
// grid BATCH, block CDIM.
// ---------------------------------------------------------------------------
__global__ __launch_bounds__(256) void mlp2_final_kernel(
    const float* __restrict__ part2, const float* __restrict__ b2,
    float* __restrict__ proj)
{
    const int b = blockIdx.x;
    const int t = threadIdx.x;

    float acc = b2[t];
    #pragma unroll
    for (int p = 0; p < KC2; ++p)
        acc += part2[((size_t)p * BATCH + b) * CDIM + t];

    __shared__ float red[CDIM];
    red[t] = acc * acc;
    __syncthreads();
    for (int off = CDIM / 2; off > 0; off >>= 1) {
        if (t < off) red[t] += red[t + off];
        __syncthreads();
    }
    const float norm = fmaxf(sqrtf(red[0]), 1e-12f);
    proj[(size_t)b * CDIM + t] = acc / norm;
}

// ---------------------------------------------------------------------------
// Kernel 5: fused sim row + per-row loss + last-block mean (t0-only ticket,
// proven benign in R4/R6). grid BATCH, block BATCH.
// ---------------------------------------------------------------------------
__global__ __launch_bounds__(128) void sim_loss_kernel(
    const float* __restrict__ proj, const float* __restrict__ temp,
    const int* __restrict__ lang, float* __restrict__ loss_part,
    unsigned* __restrict__ counter, float* __restrict__ out_loss)
{
    const int i = blockIdx.x;
    const int j = threadIdx.x;

    __shared__ float pi[CDIM];
    if (j < CDIM / 4)
        reinterpret_cast<vf4*>(pi)[j] =
            reinterpret_cast<const vf4*>(proj + (size_t)i * CDIM)[j];
    __syncthreads();

    const vf4* pj = reinterpret_cast<const vf4*>(proj + (size_t)j * CDIM);
    float acc = 0.f;
    #pragma unroll 8
    for (int c = 0; c < CDIM / 4; ++c) {
        const vf4 v = pj[c];
        acc = fmaf(pi[4 * c + 0], v.x, acc);
        acc = fmaf(pi[4 * c + 1], v.y, acc);
        acc = fmaf(pi[4 * c + 2], v.z, acc);
        acc = fmaf(pi[4 * c + 3], v.w, acc);
    }
    const float s = acc / temp[0];
    const int li = lang[i];

    __shared__ float r1[BATCH];
    __shared__ int   ci[BATCH];

    r1[j] = s;
    __syncthreads();
    for (int off = BATCH / 2; off > 0; off >>= 1) {
        if (j < off) r1[j] = fmaxf(r1[j], r1[j + off]);
        __syncthreads();
    }
    const float m = r1[0];
    __syncthreads();

    r1[j] = expf(s - m);
    __syncthreads();
    for (int off = BATCH / 2; off > 0; off >>= 1) {
        if (j < off) r1[j] += r1[j + off];
        __syncthreads();
    }
    const float lse = m + logf(r1[0]);
    __syncthreads();

    const bool sel = (lang[j] != li) && (j != i);
    r1[j] = sel ? s : 0.f;
    ci[j] = sel ? 1 : 0;
    __syncthreads();
    for (int off = BATCH / 2; off > 0; off >>= 1) {
        if (j < off) { r1[j] += r1[j + off]; ci[j] += ci[j + off]; }
        __syncthreads();
    }

    __shared__ bool last;
    if (j == 0) {
        loss_part[i] = (float)ci[0] * lse - r1[0];
        __threadfence();                         // release t0's own write
        const unsigned old = atomicAdd(counter, 1u);
        last = (old == BATCH - 1);
    }
    __syncthreads();
    if (last) {
        __threadfence();                         // acquire others' loss_part
        r1[j] = loss_part[j];
        __syncthreads();
        for (int off = BATCH / 2; off > 0; off >>= 1) {
            if (j < off) r1[j] += r1[j + off];
            __syncthreads();
        }
        if (j == 0) out_loss[0] = r1[0] / (float)BATCH;
    }
}

// ---------------------------------------------------------------------------
extern "C" void kernel_launch(void* const* d_in, const int* in_sizes, int n_in,
                              void* d_out, int out_size, void* d_ws, size_t ws_size,
                              hipStream_t stream)
{
    const float* feat = (const float*)d_in[0];
    const float* W1   = (const float*)d_in[1];
    const float* b1   = (const float*)d_in[2];
    const float* W2   = (const float*)d_in[3];
    const float* b2   = (const float*)d_in[4];
    const float* temp = (const float*)d_in[5];
    const int*   lang = (const int*)d_in[6];
    const int*   amask= (const int*)d_in[7];
    float* out = (float*)d_out;
    float* ws  = (float*)d_ws;

    float*    partial   = ws;                                      // B*SPLIT*H (8 MiB)
    float*    part1     = partial + (size_t)BATCH * SPLIT * HID;   // KC1*B*H   (8 MiB)
    float*    part2     = part1 + (size_t)KC1 * BATCH * HID;       // KC2*B*C
    float*    loss_part = part2 + (size_t)KC2 * BATCH * CDIM;      // B
    int*      cntp      = (int*)(loss_part + BATCH);               // B*SPLIT
    unsigned* tkt_loss  = (unsigned*)(cntp + BATCH * SPLIT);       // 1

    pool_partial_kernel<<<dim3(BATCH, SPLIT), 256, 0, stream>>>(
        feat, amask, partial, cntp, tkt_loss);
    mlp1_fused_kernel<<<dim3(HID / 256, BATCH / 8, KC1), 256, 0, stream>>>(
        partial, cntp, W1, part1);
    mlp2_partial_kernel<<<dim3(BATCH, KC2), 256, 0, stream>>>(
        part1, b1, W2, part2);
    mlp2_final_kernel<<<BATCH, CDIM, 0, stream>>>(part2, b2, out);
    sim_loss_kernel<<<BATCH, BATCH, 0, stream>>>(
        out, temp, lang, loss_part, tkt_loss, out + (size_t)BATCH * CDIM);
}

// Round 8
// 207.253 us; speedup vs baseline: 1.1454x; 1.1454x over previous
//
#include <hip/hip_runtime.h>
#include <math.h>

#define BATCH 128
#define SEQ   2048
#define HID   1024
#define CDIM  256
#define SPLIT 16
#define ROWS_PER (SEQ / SPLIT)   // 128
#define KC1   16                 // mlp1 k-chunks (each 64)
#define KC2   4                  // mlp2 k-chunks (each 256)

typedef float vf4 __attribute__((ext_vector_type(4)));
typedef int   vi4 __attribute__((ext_vector_type(4)));

// ---------------------------------------------------------------------------
// Kernel 1: partial masked sums over a chunk of the sequence.
// grid (BATCH, SPLIT), block 256. Thread t owns float4 at h = t*4 (256*4=HID).
// NONTEMPORAL loads: R7 A/B proved nt is worth ~29 us on this 1 GiB
// one-touch stream (plain loads pollute L2/LLC).
// ---------------------------------------------------------------------------
__global__ __launch_bounds__(256) void pool_partial_kernel(
    const float* __restrict__ feat, const int* __restrict__ mask,
    float* __restrict__ partial)
{
    const int b     = blockIdx.x;
    const int chunk = blockIdx.y;
    const int t     = threadIdx.x;

    const vf4* fp = reinterpret_cast<const vf4*>(feat) +
                    ((size_t)b * SEQ + (size_t)chunk * ROWS_PER) * (HID / 4);
    const vi4* mp = reinterpret_cast<const vi4*>(
                        mask + (size_t)b * SEQ + (size_t)chunk * ROWS_PER);

    vf4 acc = {0.f, 0.f, 0.f, 0.f};
    for (int s = 0; s < ROWS_PER; s += 8) {
        const vi4 m0 = mp[s / 4];
        const vi4 m1 = mp[s / 4 + 1];
        float mm[8];
        mm[0] = (float)m0.x; mm[1] = (float)m0.y; mm[2] = (float)m0.z; mm[3] = (float)m0.w;
        mm[4] = (float)m1.x; mm[5] = (float)m1.y; mm[6] = (float)m1.z; mm[7] = (float)m1.w;
        #pragma unroll
        for (int u = 0; u < 8; ++u) {
            const vf4 v = __builtin_nontemporal_load(&fp[(size_t)(s + u) * (HID / 4) + t]);
            acc += v * mm[u];
        }
    }
    reinterpret_cast<vf4*>(partial)[((size_t)b * SPLIT + chunk) * (HID / 4) + t] = acc;
}

// ---------------------------------------------------------------------------
// Kernel 2: mask count + reduce partials + divide -> pooled [B,H].
// grid (BATCH, 4), block 256. Block (b,cc) handles cols cc*256..+256.
// ---------------------------------------------------------------------------
__global__ __launch_bounds__(256) void pool_final_kernel(
    const float* __restrict__ partial, const int* __restrict__ mask,
    float* __restrict__ pooled)
{
    const int b  = blockIdx.x;
    const int cc = blockIdx.y;
    const int t  = threadIdx.x;

    int local = 0;
    #pragma unroll
    for (int s = t; s < SEQ; s += 256) local += mask[(size_t)b * SEQ + s];
    __shared__ int redi[256];
    redi[t] = local;
    __syncthreads();
    for (int off = 128; off > 0; off >>= 1) {
        if (t < off) redi[t] += redi[t + off];
        __syncthreads();
    }
    const float inv = 1.0f / (float)redi[0];

    const int col = cc * 256 + t;
    float a = 0.f;
    #pragma unroll
    for (int c = 0; c < SPLIT; ++c)
        a += partial[((size_t)b * SPLIT + c) * HID + col];
    pooled[(size_t)b * HID + col] = a * inv;
}

// ---------------------------------------------------------------------------
// Kernel 3: mlp1 split-K partials. W1 is [H,H] (in,out) row-major.
// grid (4 jc, 16 bg, 16 kc) = 1024 blocks, block 256.
// Block: 8 batch rows x 256 out-cols x 64 k. part1[kc][b][j].
// ---------------------------------------------------------------------------
__global__ __launch_bounds__(256) void mlp1_partial_kernel(
    const float* __restrict__ pooled, const float* __restrict__ W1,
    float* __restrict__ part1)
{
    const int jc = blockIdx.x;
    const int bg = blockIdx.y;
    const int kc = blockIdx.z;
    const int t  = threadIdx.x;

    __shared__ float ps[8][64];  // 2 KiB
    if (t < 128) {
        const int r = t >> 4;
        const int c = (t & 15) * 4;
        *reinterpret_cast<vf4*>(&ps[r][c]) =
            *reinterpret_cast<const vf4*>(&pooled[(size_t)(bg * 8 + r) * HID + kc * 64 + c]);
    }
    __syncthreads();

    const int j = jc * 256 + t;
    const float* w = W1 + (size_t)(kc * 64) * HID + j;

    float acc[8];
    #pragma unroll
    for (int r = 0; r < 8; ++r) acc[r] = 0.f;

    #pragma unroll
    for (int k = 0; k < 64; k += 8) {
        float wv[8];
        #pragma unroll
        for (int u = 0; u < 8; ++u) wv[u] = w[(size_t)(k + u) * HID];
        #pragma unroll
        for (int u = 0; u < 8; ++u) {
            #pragma unroll
            for (int r = 0; r < 8; ++r)
                acc[r] = fmaf(ps[r][k + u], wv[u], acc[r]);
        }
    }
    #pragma unroll
    for (int r = 0; r < 8; ++r)
        part1[((size_t)kc * BATCH + bg * 8 + r) * HID + j] = acc[r];
}

// ---------------------------------------------------------------------------
// Kernel 4: fused {reduce part1 + bias + relu} staging, then mlp2 split-K.
// grid (BATCH, 4 kc) = 512 blocks, block 256 (t = out col j, CDIM=256).
// Each block reduces its own disjoint 256-wide h-chunk (no redundancy).
// part2[kc][b][j].
// ---------------------------------------------------------------------------
__global__ __launch_bounds__(256) void mlp2_partial_kernel(
    const float* __restrict__ part1, const float* __restrict__ b1,
    const float* __restrict__ W2, float* __restrict__ part2)
{
    const int b  = blockIdx.x;
    const int kc = blockIdx.y;
    const int t  = threadIdx.x;

    __shared__ float hs[256];  // 1 KiB
    float s = b1[kc * 256 + t];
    #pragma unroll
    for (int p = 0; p < KC1; ++p)
        s += part1[((size_t)p * BATCH + b) * HID + kc * 256 + t];
    hs[t] = fmaxf(s, 0.f);
    __syncthreads();

    const float* w = W2 + (size_t)(kc * 256) * CDIM + t;
    float acc = 0.f;
    #pragma unroll
    for (int k = 0; k < 256; k += 8) {
        float wv[8];
        #pragma unroll
        for (int u = 0; u < 8; ++u) wv[u] = w[(size_t)(k + u) * CDIM];
        #pragma unroll
        for (int u = 0; u < 8; ++u) acc = fmaf(hs[k + u], wv[u], acc);
    }
    part2[((size_t)kc * BATCH + b) * CDIM + t] = acc;
}

// ---------------------------------------------------------------------------
// Kernel 5: reduce part2 + bias + L2-normalize -> proj (d_out).
// grid BATCH, block CDIM.
// ---------------------------------------------------------------------------
__global__ __launch_bounds__(256) void mlp2_final_kernel(
    const float* __restrict__ part2, const float* __restrict__ b2,
    float* __restrict__ proj)
{
    const int b = blockIdx.x;
    const int t = threadIdx.x;

    float acc = b2[t];
    #pragma unroll
    for (int p = 0; p < KC2; ++p)
        acc += part2[((size_t)p * BATCH + b) * CDIM + t];

    __shared__ float red[CDIM];
    red[t] = acc * acc;
    __syncthreads();
    for (int off = CDIM / 2; off > 0; off >>= 1) {
        if (t < off) red[t] += red[t + off];
        __syncthreads();
    }
    const float norm = fmaxf(sqrtf(red[0]), 1e-12f);
    proj[(size_t)b * CDIM + t] = acc / norm;
}

// ---------------------------------------------------------------------------
// Kernel 6: fused sim row + per-row loss. grid BATCH, block BATCH.
// ---------------------------------------------------------------------------
__global__ __launch_bounds__(128) void sim_loss_kernel(
    const float* __restrict__ proj, const float* __restrict__ temp,
    const int* __restrict__ lang, float* __restrict__ loss_part)
{
    const int i = blockIdx.x;
    const int j = threadIdx.x;

    __shared__ float pi[CDIM];
    if (j < CDIM / 4)
        reinterpret_cast<vf4*>(pi)[j] =
            reinterpret_cast<const vf4*>(proj + (size_t)i * CDIM)[j];
    __syncthreads();

    const vf4* pj = reinterpret_cast<const vf4*>(proj + (size_t)j * CDIM);
    float acc = 0.f;
    #pragma unroll 8
    for (int c = 0; c < CDIM / 4; ++c) {
        const vf4 v = pj[c];
        acc = fmaf(pi[4 * c + 0], v.x, acc);
        acc = fmaf(pi[4 * c + 1], v.y, acc);
        acc = fmaf(pi[4 * c + 2], v.z, acc);
        acc = fmaf(pi[4 * c + 3], v.w, acc);
    }
    const float s = acc / temp[0];
    const int li = lang[i];

    __shared__ float r1[BATCH];
    __shared__ int   ci[BATCH];

    r1[j] = s;
    __syncthreads();
    for (int off = BATCH / 2; off > 0; off >>= 1) {
        if (j < off) r1[j] = fmaxf(r1[j], r1[j + off]);
        __syncthreads();
    }
    const float m = r1[0];
    __syncthreads();

    r1[j] = expf(s - m);
    __syncthreads();
    for (int off = BATCH / 2; off > 0; off >>= 1) {
        if (j < off) r1[j] += r1[j + off];
        __syncthreads();
    }
    const float lse = m + logf(r1[0]);
    __syncthreads();

    const bool sel = (lang[j] != li) && (j != i);
    r1[j] = sel ? s : 0.f;
    ci[j] = sel ? 1 : 0;
    __syncthreads();
    for (int off = BATCH / 2; off > 0; off >>= 1) {
        if (j < off) { r1[j] += r1[j + off]; ci[j] += ci[j + off]; }
        __syncthreads();
    }
    if (j == 0) loss_part[i] = (float)ci[0] * lse - r1[0];
}

// ---------------------------------------------------------------------------
// Kernel 7: mean of per-row losses -> out[B*C].
// ---------------------------------------------------------------------------
__global__ __launch_bounds__(128) void loss_reduce_kernel(
    const float* __restrict__ loss_part, float* __restrict__ out)
{
    const int t = threadIdx.x;
    __shared__ float red[BATCH];
    red[t] = loss_part[t];
    __syncthreads();
    for (int off = BATCH / 2; off > 0; off >>= 1) {
        if (t < off) red[t] += red[t + off];
        __syncthreads();
    }
    if (t == 0) out[0] = red[0] / (float)BATCH;
}

// ---------------------------------------------------------------------------
extern "C" void kernel_launch(void* const* d_in, const int* in_sizes, int n_in,
                              void* d_out, int out_size, void* d_ws, size_t ws_size,
                              hipStream_t stream)
{
    const float* feat = (const float*)d_in[0];
    const float* W1   = (const float*)d_in[1];
    const float* b1   = (const float*)d_in[2];
    const float* W2   = (const float*)d_in[3];
    const float* b2   = (const float*)d_in[4];
    const float* temp = (const float*)d_in[5];
    const int*   lang = (const int*)d_in[6];
    const int*   amask= (const int*)d_in[7];
    float* out = (float*)d_out;
    float* ws  = (float*)d_ws;

    float* partial   = ws;                                        // B*SPLIT*H   (8 MB)
    float* pooled    = partial + (size_t)BATCH * SPLIT * HID;     // B*H
    float* part1     = pooled + (size_t)BATCH * HID;              // KC1*B*H     (8 MB)
    float* part2     = part1 + (size_t)KC1 * BATCH * HID;         // KC2*B*C
    float* loss_part = part2 + (size_t)KC2 * BATCH * CDIM;        // B

    pool_partial_kernel<<<dim3(BATCH, SPLIT), 256, 0, stream>>>(feat, amask, partial);
    pool_final_kernel<<<dim3(BATCH, 4), 256, 0, stream>>>(partial, amask, pooled);
    mlp1_partial_kernel<<<dim3(HID / 256, BATCH / 8, KC1), 256, 0, stream>>>(pooled, W1, part1);
    mlp2_partial_kernel<<<dim3(BATCH, KC2), 256, 0, stream>>>(part1, b1, W2, part2);
    mlp2_final_kernel<<<BATCH, CDIM, 0, stream>>>(part2, b2, out);
    sim_loss_kernel<<<BATCH, BATCH, 0, stream>>>(out, temp, lang, loss_part);
    loss_reduce_kernel<<<1, BATCH, 0, stream>>>(loss_part, out + (size_t)BATCH * CDIM);
}